// Round 12
// baseline (42.689 us; speedup 1.0000x reference)
//
#include <hip/hip_runtime.h>

#define IMG   512
#define H     16      // output rows per wave
#define WPB   4       // waves per block (each wave = its own strip, no sync)
#define NXCD  8

__global__ __launch_bounds__(256)
void mean_filter_deep(const float* __restrict__ in, float* __restrict__ out,
                      int bands, int cpx) {
    // bijective XCD-contiguous swizzle (nwg % 8 == 0)
    const int hw  = blockIdx.x;
    const int bid = (hw % NXCD) * cpx + (hw / NXCD);
    const int plane = bid / bands;
    const int band  = bid - plane * bands;
    const int wid   = threadIdx.x >> 6;     // 0..3: wave's strip within the band
    const int lane  = threadIdx.x & 63;
    const int y0    = band * (H * WPB) + wid * H;
    const int x8    = lane * 8;             // 8 columns per lane

    const float* __restrict__ src = in  + (size_t)plane * IMG * IMG + x8;
    float*       __restrict__ dst = out + (size_t)plane * IMG * IMG + x8;

    // per-column horizontal reciprocal counts (constant down the strip)
    float invcx[8];
#pragma unroll
    for (int j = 0; j < 8; ++j) {
        const int x  = x8 + j;
        const int cx = min(x + 2, IMG - 1) - max(x - 2, 0) + 1;
        invcx[j] = 1.0f / (float)cx;
    }

    // Load ALL 20 rows (H + 4 halo) up front: 40 independent dwordx4 loads
    // in flight per wave -> deep MLP. Static indexing keeps R[] in registers.
    float4 R[H + 4][2];
#pragma unroll
    for (int k = 0; k < H + 4; ++k) {
        const int y = y0 + k - 2;
        if ((unsigned)y < (unsigned)IMG) {   // wave-uniform branch
            R[k][0] = *(const float4*)(src + (size_t)y * IMG);
            R[k][1] = *(const float4*)(src + (size_t)y * IMG + 4);
        } else {
            R[k][0] = make_float4(0.f, 0.f, 0.f, 0.f);
            R[k][1] = make_float4(0.f, 0.f, 0.f, 0.f);
        }
    }
    // Pin all load issues before any compute (compiler would otherwise sink
    // loads to uses and collapse the pipeline back to depth ~2).
    __builtin_amdgcn_sched_barrier(0);

#pragma unroll
    for (int i = 0; i < H; ++i) {
        const int y = y0 + i;

        // vertical 5-sums for own 8 columns (rows i..i+4 of R)
        const float v0 = R[i][0].x + R[i+1][0].x + R[i+2][0].x + R[i+3][0].x + R[i+4][0].x;
        const float v1 = R[i][0].y + R[i+1][0].y + R[i+2][0].y + R[i+3][0].y + R[i+4][0].y;
        const float v2 = R[i][0].z + R[i+1][0].z + R[i+2][0].z + R[i+3][0].z + R[i+4][0].z;
        const float v3 = R[i][0].w + R[i+1][0].w + R[i+2][0].w + R[i+3][0].w + R[i+4][0].w;
        const float v4 = R[i][1].x + R[i+1][1].x + R[i+2][1].x + R[i+3][1].x + R[i+4][1].x;
        const float v5 = R[i][1].y + R[i+1][1].y + R[i+2][1].y + R[i+3][1].y + R[i+4][1].y;
        const float v6 = R[i][1].z + R[i+1][1].z + R[i+2][1].z + R[i+3][1].z + R[i+4][1].z;
        const float v7 = R[i][1].w + R[i+1][1].w + R[i+2][1].w + R[i+3][1].w + R[i+4][1].w;

        // horizontal neighbors via register cross-lane (no LDS, no barrier)
        float l0 = __shfl_up(v6, 1);    // col x8-2
        float l1 = __shfl_up(v7, 1);    // col x8-1
        float q0 = __shfl_down(v0, 1);  // col x8+8
        float q1 = __shfl_down(v1, 1);  // col x8+9
        if (lane == 0)  { l0 = 0.f; l1 = 0.f; }
        if (lane == 63) { q0 = 0.f; q1 = 0.f; }

        const int   cy    = min(y + 2, IMG - 1) - max(y - 2, 0) + 1;
        const float invcy = 1.0f / (float)cy;

        float4 oa, ob;
        oa.x = (l0 + l1 + v0 + v1 + v2) * (invcy * invcx[0]);
        oa.y = (l1 + v0 + v1 + v2 + v3) * (invcy * invcx[1]);
        oa.z = (v0 + v1 + v2 + v3 + v4) * (invcy * invcx[2]);
        oa.w = (v1 + v2 + v3 + v4 + v5) * (invcy * invcx[3]);
        ob.x = (v2 + v3 + v4 + v5 + v6) * (invcy * invcx[4]);
        ob.y = (v3 + v4 + v5 + v6 + v7) * (invcy * invcx[5]);
        ob.z = (v4 + v5 + v6 + v7 + q0) * (invcy * invcx[6]);
        ob.w = (v5 + v6 + v7 + q0 + q1) * (invcy * invcx[7]);

        *(float4*)(dst + (size_t)y * IMG)     = oa;
        *(float4*)(dst + (size_t)y * IMG + 4) = ob;
    }
}

extern "C" void kernel_launch(void* const* d_in, const int* in_sizes, int n_in,
                              void* d_out, int out_size, void* d_ws, size_t ws_size,
                              hipStream_t stream) {
    const float* x = (const float*)d_in[0];
    float* out = (float*)d_out;
    const int planes = in_sizes[0] / (IMG * IMG);    // 96
    const int bands  = IMG / (H * WPB);              // 8 bands of 64 rows
    const int nwg    = planes * bands;               // 768 (% 8 == 0)
    const int cpx    = nwg / NXCD;                   // 96
    mean_filter_deep<<<dim3(nwg), dim3(256), 0, stream>>>(x, out, bands, cpx);
}

// Round 13
// 36.355 us; speedup vs baseline: 1.1742x; 1.1742x over previous
//
#include <hip/hip_runtime.h>

#define IMG   512
#define H     16      // output rows per wave
#define WPB   4       // waves per block (each wave = its own strip, no sync)
#define NXCD  8

__global__ __launch_bounds__(256)
void mean_filter_wave4(const float* __restrict__ in, float* __restrict__ out,
                       int bands, int cpx) {
    // bijective XCD-contiguous swizzle (nwg % 8 == 0)
    const int hw  = blockIdx.x;
    const int bid = (hw % NXCD) * cpx + (hw / NXCD);
    const int plane = bid / bands;
    const int band  = bid - plane * bands;
    const int wid   = threadIdx.x >> 6;     // 0..3: wave's strip within the band
    const int lane  = threadIdx.x & 63;
    const int y0    = band * (H * WPB) + wid * H;
    const int x8    = lane * 8;             // 8 columns per lane

    const float* __restrict__ src = in  + (size_t)plane * IMG * IMG + x8;
    float*       __restrict__ dst = out + (size_t)plane * IMG * IMG + x8;

    // per-column horizontal reciprocal counts (constant down the strip)
    float invcx[8];
#pragma unroll
    for (int j = 0; j < 8; ++j) {
        const int x  = x8 + j;
        const int cx = min(x + 2, IMG - 1) - max(x - 2, 0) + 1;
        invcx[j] = 1.0f / (float)cx;
    }

    // register ring: rows y-2..y+2, 8 floats each (two float4 halves a/b)
    float4 a0, a1, a2, a3, a4, b0, b1, b2, b3, b4;
    auto loadrow = [&](int y, float4& a, float4& b) {
        if ((unsigned)y < (unsigned)IMG) {
            a = *(const float4*)(src + (size_t)y * IMG);
            b = *(const float4*)(src + (size_t)y * IMG + 4);
        } else {
            a = make_float4(0.f, 0.f, 0.f, 0.f);
            b = make_float4(0.f, 0.f, 0.f, 0.f);
        }
    };

    loadrow(y0 - 2, a1, b1);
    loadrow(y0 - 1, a2, b2);
    loadrow(y0,     a3, b3);
    loadrow(y0 + 1, a4, b4);

#pragma unroll
    for (int i = 0; i < H; ++i) {
        const int y = y0 + i;
        a0 = a1; b0 = b1; a1 = a2; b1 = b2; a2 = a3; b2 = b3; a3 = a4; b3 = b4;
        loadrow(y + 2, a4, b4);

        // vertical 5-sums for own 8 columns
        const float v0 = a0.x + a1.x + a2.x + a3.x + a4.x;
        const float v1 = a0.y + a1.y + a2.y + a3.y + a4.y;
        const float v2 = a0.z + a1.z + a2.z + a3.z + a4.z;
        const float v3 = a0.w + a1.w + a2.w + a3.w + a4.w;
        const float v4 = b0.x + b1.x + b2.x + b3.x + b4.x;
        const float v5 = b0.y + b1.y + b2.y + b3.y + b4.y;
        const float v6 = b0.z + b1.z + b2.z + b3.z + b4.z;
        const float v7 = b0.w + b1.w + b2.w + b3.w + b4.w;

        // horizontal neighbors via register cross-lane (no LDS, no barrier)
        float l0 = __shfl_up(v6, 1);    // col x8-2
        float l1 = __shfl_up(v7, 1);    // col x8-1
        float q0 = __shfl_down(v0, 1);  // col x8+8
        float q1 = __shfl_down(v1, 1);  // col x8+9
        if (lane == 0)  { l0 = 0.f; l1 = 0.f; }
        if (lane == 63) { q0 = 0.f; q1 = 0.f; }

        const int   cy    = min(y + 2, IMG - 1) - max(y - 2, 0) + 1;
        const float invcy = 1.0f / (float)cy;

        float4 oa, ob;
        oa.x = (l0 + l1 + v0 + v1 + v2) * (invcy * invcx[0]);
        oa.y = (l1 + v0 + v1 + v2 + v3) * (invcy * invcx[1]);
        oa.z = (v0 + v1 + v2 + v3 + v4) * (invcy * invcx[2]);
        oa.w = (v1 + v2 + v3 + v4 + v5) * (invcy * invcx[3]);
        ob.x = (v2 + v3 + v4 + v5 + v6) * (invcy * invcx[4]);
        ob.y = (v3 + v4 + v5 + v6 + v7) * (invcy * invcx[5]);
        ob.z = (v4 + v5 + v6 + v7 + q0) * (invcy * invcx[6]);
        ob.w = (v5 + v6 + v7 + q0 + q1) * (invcy * invcx[7]);

        *(float4*)(dst + (size_t)y * IMG)     = oa;
        *(float4*)(dst + (size_t)y * IMG + 4) = ob;
    }
}

extern "C" void kernel_launch(void* const* d_in, const int* in_sizes, int n_in,
                              void* d_out, int out_size, void* d_ws, size_t ws_size,
                              hipStream_t stream) {
    const float* x = (const float*)d_in[0];
    float* out = (float*)d_out;
    const int planes = in_sizes[0] / (IMG * IMG);    // 96
    const int bands  = IMG / (H * WPB);              // 8 bands of 64 rows
    const int nwg    = planes * bands;               // 768 (% 8 == 0)
    const int cpx    = nwg / NXCD;                   // 96
    mean_filter_wave4<<<dim3(nwg), dim3(256), 0, stream>>>(x, out, bands, cpx);
}